// Round 2
// baseline (413.823 us; speedup 1.0000x reference)
//
#include <hip/hip_runtime.h>

#define Hh 64
#define Ww 64
#define Cc 512
#define Bb 16
#define NTOK (1 + Hh * Ww)   // 4097
#define TW 8                 // outputs per thread along w
#define TH 4                 // outputs per thread along h

// ---------------------------------------------------------------------------
// Prep kernel: combine w7 + (padded) w5 + (padded) w3 + identity delta into a
// single effective 7x7 kernel per channel, stored TRANSPOSED [tap][channel]
// so the conv kernel's per-lane tap reads are coalesced. Combine biases and
// copy the cls tokens straight through to the output.
// ---------------------------------------------------------------------------
__global__ void ppeg_prep(const float* __restrict__ w7, const float* __restrict__ b7,
                          const float* __restrict__ w5, const float* __restrict__ b5,
                          const float* __restrict__ w3, const float* __restrict__ b3,
                          const float* __restrict__ x, float* __restrict__ wt,
                          float* __restrict__ beff, float* __restrict__ out) {
    int idx = blockIdx.x * blockDim.x + threadIdx.x;
    if (idx < Cc * 49) {
        int c = idx / 49, t = idx % 49;
        int r = t / 7, s = t % 7;
        float v = w7[idx];
        if (r >= 1 && r <= 5 && s >= 1 && s <= 5) v += w5[c * 25 + (r - 1) * 5 + (s - 1)];
        if (r >= 2 && r <= 4 && s >= 2 && s <= 4) v += w3[c * 9 + (r - 2) * 3 + (s - 2)];
        if (t == 24) v += 1.0f;               // identity (center tap)
        wt[t * Cc + c] = v;                   // transposed store
    }
    if (idx < Cc) beff[idx] = b7[idx] + b5[idx] + b3[idx];
    if (idx < Bb * Cc) {
        int b = idx / Cc, c = idx % Cc;
        size_t o = (size_t)b * NTOK * Cc + c;
        out[o] = x[o];                        // cls token pass-through
    }
}

// ---------------------------------------------------------------------------
// Main conv kernel. No LDS. Block = (64 channel-lanes, 4 h-strips). Each
// thread computes a 4x8 output tile for one channel: 10 input rows stream
// through a 14-float register window, each loaded row feeds up to 4 output
// rows (2.4x fewer loads/output than 1-row threads). 49 combined taps are
// read once per thread from the transposed weight array (coalesced, L2-hot)
// and live in registers for the whole kernel.
// ---------------------------------------------------------------------------
__global__ __launch_bounds__(256, 4)
void ppeg_conv(const float* __restrict__ x, const float* __restrict__ wt,
               const float* __restrict__ beff, float* __restrict__ out) {
    const int tx = threadIdx.x;        // channel lane 0..63
    const int ty = threadIdx.y;        // h-strip 0..3 (wave-uniform)
    const int cb = blockIdx.y * 64;
    const int c  = cb + tx;
    const int b  = blockIdx.z;
    const int sp = blockIdx.x;         // 0..31 : 4 h-blocks x 8 w-tiles
    const int hblk  = sp >> 3;
    const int wblk  = sp & 7;
    const int oh0   = hblk * 16 + ty * TH;   // first of TH output rows
    const int wbase = wblk * TW;

    // 49 taps -> registers (coalesced 256B/wave loads, L2-resident).
    float wk[49];
#pragma unroll
    for (int k = 0; k < 49; ++k) wk[k] = wt[k * Cc + c];
    const float bias = beff[c];

    const float* xb = x + ((size_t)b * NTOK + 1) * Cc + c;   // pixel (0,0), channel c

    float acc[TH][TW];
#pragma unroll
    for (int o = 0; o < TH; ++o)
#pragma unroll
        for (int j = 0; j < TW; ++j) acc[o][j] = bias;

    const bool interior = (wblk != 0) && (wblk != 7);

#pragma unroll
    for (int ir_off = 0; ir_off < TH + 6; ++ir_off) {        // 10 input rows
        const int ir = oh0 - 3 + ir_off;
        if (ir < 0 || ir >= Hh) continue;                    // wave-uniform
        const float* xrow = xb + (size_t)ir * Ww * Cc;
        float v[TW + 6];
        if (interior) {
#pragma unroll
            for (int j = 0; j < TW + 6; ++j)
                v[j] = xrow[(size_t)(wbase - 3 + j) * Cc];
        } else {
#pragma unroll
            for (int j = 0; j < TW + 6; ++j) {
                const int wc = wbase + j - 3;
                v[j] = (wc >= 0 && wc < Ww) ? xrow[(size_t)wc * Cc] : 0.0f;
            }
        }
#pragma unroll
        for (int o = 0; o < TH; ++o) {
            const int r = ir_off - o;                        // compile-time
            if (r < 0 || r > 6) continue;
#pragma unroll
            for (int j = 0; j < TW; ++j)
#pragma unroll
                for (int s = 0; s < 7; ++s)
                    acc[o][j] = fmaf(wk[r * 7 + s], v[j + s], acc[o][j]);
        }
    }

#pragma unroll
    for (int o = 0; o < TH; ++o) {
        float* orow = out + ((size_t)b * NTOK + 1 + (size_t)(oh0 + o) * Ww + wbase) * Cc + c;
#pragma unroll
        for (int j = 0; j < TW; ++j) orow[(size_t)j * Cc] = acc[o][j];
    }
}

extern "C" void kernel_launch(void* const* d_in, const int* in_sizes, int n_in,
                              void* d_out, int out_size, void* d_ws, size_t ws_size,
                              hipStream_t stream) {
    const float* x  = (const float*)d_in[0];
    const float* w7 = (const float*)d_in[1];
    const float* b7 = (const float*)d_in[2];
    const float* w5 = (const float*)d_in[3];
    const float* b5 = (const float*)d_in[4];
    const float* w3 = (const float*)d_in[5];
    const float* b3 = (const float*)d_in[6];
    float* out = (float*)d_out;

    float* wt   = (float*)d_ws;          // 49*Cc floats, transposed [tap][channel]
    float* beff = wt + 49 * Cc;          // Cc floats

    ppeg_prep<<<(Cc * 49 + 255) / 256, 256, 0, stream>>>(w7, b7, w5, b5, w3, b3,
                                                         x, wt, beff, out);

    dim3 grid((Hh / (TH * 4)) * (Ww / TW), Cc / 64, Bb);   // (32, 8, 16)
    dim3 block(64, 4);
    ppeg_conv<<<grid, block, 0, stream>>>(x, wt, beff, out);
}

// Round 3
// 327.902 us; speedup vs baseline: 1.2620x; 1.2620x over previous
//
#include <hip/hip_runtime.h>

#define Hh 64
#define Ww 64
#define Cc 512
#define Bb 16
#define NTOK (1 + Hh * Ww)   // 4097
#define TW 8                 // outputs per thread along w
#define TH 2                 // outputs per thread along h

// ---------------------------------------------------------------------------
// Prep kernel: combine w7 + (padded) w5 + (padded) w3 + identity delta into a
// single effective 7x7 kernel per channel, stored TRANSPOSED [tap][channel]
// so conv-side tap reads are coalesced (lane = channel). Combine biases and
// copy the cls tokens straight through to the output.
// ---------------------------------------------------------------------------
__global__ void ppeg_prep(const float* __restrict__ w7, const float* __restrict__ b7,
                          const float* __restrict__ w5, const float* __restrict__ b5,
                          const float* __restrict__ w3, const float* __restrict__ b3,
                          const float* __restrict__ x, float* __restrict__ wt,
                          float* __restrict__ beff, float* __restrict__ out) {
    int idx = blockIdx.x * blockDim.x + threadIdx.x;
    if (idx < Cc * 49) {
        int c = idx / 49, t = idx % 49;
        int r = t / 7, s = t % 7;
        float v = w7[idx];
        if (r >= 1 && r <= 5 && s >= 1 && s <= 5) v += w5[c * 25 + (r - 1) * 5 + (s - 1)];
        if (r >= 2 && r <= 4 && s >= 2 && s <= 4) v += w3[c * 9 + (r - 2) * 3 + (s - 2)];
        if (t == 24) v += 1.0f;               // identity (center tap)
        wt[t * Cc + c] = v;                   // transposed store
    }
    if (idx < Cc) beff[idx] = b7[idx] + b5[idx] + b3[idx];
    if (idx < Bb * Cc) {
        int b = idx / Cc, c = idx % Cc;
        size_t o = (size_t)b * NTOK * Cc + c;
        out[o] = x[o];                        // cls token pass-through
    }
}

// ---------------------------------------------------------------------------
// Main conv kernel. No LDS, no spills BY DESIGN: the kernel-row-chunked loop
// keeps only 7 taps + 16 accumulators + 14-float window live (~50 VGPRs), so
// the compiler's 64-VGPR occupancy target is satisfiable without scratch
// (R1's +230MB WRITE_SIZE was spill traffic from a 110-reg live set).
// Each thread: 2x8 output tile for one channel. Taps re-read per kernel row
// from the transposed slab (12.5 KB/block, L1-hot); input rows re-read 2.8x
// (L1/L2-hot), which trades cheap cache bandwidth for zero scratch.
// ---------------------------------------------------------------------------
__global__ __launch_bounds__(256)
void ppeg_conv(const float* __restrict__ x, const float* __restrict__ wt,
               const float* __restrict__ beff, float* __restrict__ out) {
    const int tx = threadIdx.x;        // channel lane 0..63
    const int ty = threadIdx.y;        // h-strip 0..3 (wave-uniform)
    const int cb = blockIdx.y * 64;
    const int c  = cb + tx;
    const int b  = blockIdx.z;
    const int sp = blockIdx.x;         // 0..63 : 8 h-blocks x 8 w-tiles
    const int hblk  = sp >> 3;
    const int wblk  = sp & 7;
    const int oh0   = hblk * (TH * 4) + ty * TH;   // first of TH output rows
    const int wbase = wblk * TW;

    const float* xb = x + ((size_t)b * NTOK + 1) * Cc + c;   // pixel (0,0), channel c

    const float bias = beff[c];
    float acc[TH][TW];
#pragma unroll
    for (int o = 0; o < TH; ++o)
#pragma unroll
        for (int j = 0; j < TW; ++j) acc[o][j] = bias;

    const bool interior = (wblk != 0) && (wblk != 7);

#pragma unroll
    for (int r = 0; r < 7; ++r) {               // kernel row chunk: 7 taps live
        float tap[7];
#pragma unroll
        for (int s = 0; s < 7; ++s) tap[s] = wt[(r * 7 + s) * Cc + c];

#pragma unroll
        for (int o = 0; o < TH; ++o) {
            const int ir = oh0 + o + r - 3;
            if (ir < 0 || ir >= Hh) continue;   // wave-uniform (oh0 fixed per wave)
            const float* xrow = xb + (size_t)ir * Ww * Cc;
            float v[TW + 6];
            if (interior) {
#pragma unroll
                for (int j = 0; j < TW + 6; ++j)
                    v[j] = xrow[(size_t)(wbase - 3 + j) * Cc];
            } else {
#pragma unroll
                for (int j = 0; j < TW + 6; ++j) {
                    const int wc = wbase + j - 3;
                    v[j] = (wc >= 0 && wc < Ww) ? xrow[(size_t)wc * Cc] : 0.0f;
                }
            }
#pragma unroll
            for (int j = 0; j < TW; ++j)
#pragma unroll
                for (int s = 0; s < 7; ++s)
                    acc[o][j] = fmaf(tap[s], v[j + s], acc[o][j]);
        }
    }

#pragma unroll
    for (int o = 0; o < TH; ++o) {
        float* orow = out + ((size_t)b * NTOK + 1 + (size_t)(oh0 + o) * Ww + wbase) * Cc + c;
#pragma unroll
        for (int j = 0; j < TW; ++j) orow[(size_t)j * Cc] = acc[o][j];
    }
}

extern "C" void kernel_launch(void* const* d_in, const int* in_sizes, int n_in,
                              void* d_out, int out_size, void* d_ws, size_t ws_size,
                              hipStream_t stream) {
    const float* x  = (const float*)d_in[0];
    const float* w7 = (const float*)d_in[1];
    const float* b7 = (const float*)d_in[2];
    const float* w5 = (const float*)d_in[3];
    const float* b5 = (const float*)d_in[4];
    const float* w3 = (const float*)d_in[5];
    const float* b3 = (const float*)d_in[6];
    float* out = (float*)d_out;

    float* wt   = (float*)d_ws;          // 49*Cc floats, transposed [tap][channel]
    float* beff = wt + 49 * Cc;          // Cc floats

    ppeg_prep<<<(Cc * 49 + 255) / 256, 256, 0, stream>>>(w7, b7, w5, b5, w3, b3,
                                                         x, wt, beff, out);

    dim3 grid((Hh / (TH * 4)) * (Ww / TW), Cc / 64, Bb);   // (64, 8, 16)
    dim3 block(64, 4);
    ppeg_conv<<<grid, block, 0, stream>>>(x, wt, beff, out);
}